// Round 4
// baseline (578.786 us; speedup 1.0000x reference)
//
#include <hip/hip_runtime.h>
#include <cstdint>
#include <cstddef>

#define DIM 4096
#define SEQ 2048
#define NH 32
#define NKV 8
#define HD 128
#define QKVN 6144

typedef __bf16 bf16_t;
typedef __bf16 bf16x8 __attribute__((ext_vector_type(8)));
typedef __bf16 bf16x4 __attribute__((ext_vector_type(4)));
typedef __bf16 bf16x2 __attribute__((ext_vector_type(2)));
typedef float f32x4 __attribute__((ext_vector_type(4)));
typedef int int4v __attribute__((ext_vector_type(4)));

__device__ __forceinline__ f32x4 mfma16(bf16x8 a, bf16x8 b, f32x4 c) {
  return __builtin_amdgcn_mfma_f32_16x16x32_bf16(a, b, c, 0, 0, 0);
}

__device__ __forceinline__ void async16(const bf16_t* g, bf16_t* l) {
  __builtin_amdgcn_global_load_lds((__attribute__((address_space(1))) void*)g,
                                   (__attribute__((address_space(3))) void*)l,
                                   16, 0, 0);
}

__device__ __forceinline__ int pack2(float a, float b) {
  bf16x2 h = { (bf16_t)a, (bf16_t)b };
  return __builtin_bit_cast(int, h);
}

// rule #18: inline-asm waits must be followed by sched_barrier(0)
#define LGKM0() do { asm volatile("s_waitcnt lgkmcnt(0)" ::: "memory"); \
                     __builtin_amdgcn_sched_barrier(0); } while (0)
#define VMW4() do { asm volatile("s_waitcnt vmcnt(4)" ::: "memory"); \
                    __builtin_amdgcn_sched_barrier(0); } while (0)

// ---------------- cast x (fp32 -> bf16), 4 elems/thread ----------------
__global__ void cast_x(const float* __restrict__ x, bf16_t* __restrict__ xb) {
  int i = blockIdx.x * 256 + threadIdx.x;
  const float4 v = ((const float4*)x)[i];
  bf16x4 o = { (bf16_t)v.x, (bf16_t)v.y, (bf16_t)v.z, (bf16_t)v.w };
  *(bf16x4*)(xb + (size_t)i * 4) = o;
}

// ------- transpose-cast: src fp32 (Kdim x Ncols) -> dst bf16 (Ncols x Kdim) -------
__global__ void tcast(const float* __restrict__ src, bf16_t* __restrict__ dst,
                      int Ncols, int Kdim) {
  __shared__ float tile[32][33];
  int n0 = blockIdx.x * 32, k0 = blockIdx.y * 32;
  int tx = threadIdx.x, ty = threadIdx.y;  // 32 x 8
#pragma unroll
  for (int r = 0; r < 4; r++)
    tile[ty + 8 * r][tx] = src[(size_t)(k0 + ty + 8 * r) * Ncols + n0 + tx];
  __syncthreads();
#pragma unroll
  for (int r = 0; r < 4; r++)
    dst[(size_t)(n0 + ty + 8 * r) * Kdim + k0 + tx] = (bf16_t)tile[tx][ty + 8 * r];
}

// ---------------- GEMM: 256x256 tile, BK=64, wave tile 128x64 (m201 geom) -----
// C = A @ Bt^T.  LDS 128 KiB, K-half-major: As/Bs[buf][s][256 rows][32 cols].
// 4 uniform 16-MFMA phases/K-tile: {lo x s0, lo x s1, hi x s0, hi x s1};
// ds_reads 8/8/4/4 (B-frags register-resident for the whole tile).
// Staging per K-half (4 loads, contiguous 16KB): tile t's P0/P1 issue
// Kh0/Kh1 of t+1; waits are vmcnt(4) at P0-end (gates s1 reads) and P3-end
// (gates next tile's s0) -- >=4 loads always in flight, deadline 3-4 phases
// after issue.  16B-group swizzle cg^=(row&3) (balanced banks: 8 cyc/read).
// Split-K via blockIdx.z (partial tile into Cp, reduced by addf4).
__global__ __launch_bounds__(512) void gemm256(const bf16_t* __restrict__ A,
                                               const bf16_t* __restrict__ Bt,
                                               float* __restrict__ C,
                                               float* __restrict__ Cp,
                                               int M, int N, int K, int Kloc) {
  __shared__ bf16_t As[2][16384];  // [buf][s*8192 + row*32 + col]
  __shared__ bf16_t Bs[2][16384];
  const int t = threadIdx.x;
  const int lane = t & 63;
  const int l15 = lane & 15, quad = lane >> 4;
  const int w = t >> 6, wm = w >> 2, wn = w & 3;  // 2 x 4 wave grid

  // bijective XCD swizzle (nwg % 8 == 0 both call sites)
  const int gx = gridDim.x;
  const int nwg = gx * gridDim.y;
  const int id = blockIdx.y * gx + blockIdx.x;
  const int swz = (id & 7) * (nwg >> 3) + (id >> 3);
  const int bm = (swz / gx) * 256, bn = (swz % gx) * 256;
  const int kbase = blockIdx.z * Kloc;
  float* __restrict__ Cd = blockIdx.z ? Cp : C;

  // staging: one call = 8KB = 128 rows x 64B; thread t -> row t>>2, 16B-grp t&3.
  // LDS grp (t&3) holds global grp (t&3)^(row&3)  (self-inverse swizzle).
  const int srow = t >> 2;
  const int gcol = ((t & 3) ^ (srow & 3)) << 3;
  const bf16_t* gA = A + (size_t)(bm + srow) * K + kbase + gcol;
  const bf16_t* gB = Bt + (size_t)(bn + srow) * K + kbase + gcol;
  const int ldst = t * 8;

  // fragment read column: global grp = quad -> LDS grp = quad^(row&3), row&3==l15&3
  const int fcol = ((quad ^ (l15 & 3)) << 3);

  f32x4 acc[8][4] = {};
  bf16x8 af[4], bfr[4][2];

  auto stKh = [&](int b2, int s, int kk) {  // 4 loads: A p0,p1 + B p0,p1
    async16(gA + kk + s * 32, &As[b2][s * 8192 + ldst]);
    async16(gA + (size_t)128 * K + kk + s * 32, &As[b2][s * 8192 + 4096 + ldst]);
    async16(gB + kk + s * 32, &Bs[b2][s * 8192 + ldst]);
    async16(gB + (size_t)128 * K + kk + s * 32, &Bs[b2][s * 8192 + 4096 + ldst]);
  };

  // prologue: both K-halves of tile 0; wait Kh0 only (Kh1 stays in flight)
  stKh(0, 0, 0);
  stKh(0, 1, 0);
  VMW4();
  __builtin_amdgcn_s_barrier();

  const int nkt = Kloc >> 6;
  for (int kt = 0; kt < nkt; ++kt) {
    const int b2 = kt & 1, bn2 = b2 ^ 1;
    const int kn = (kt + 1 == nkt) ? 0 : (kt + 1) << 6;  // wrap-stage (dead) tail

    // ---- P0: lo rows x s0 ----
#pragma unroll
    for (int mi = 0; mi < 4; mi++)
      af[mi] = *(const bf16x8*)&As[b2][(wm * 128 + mi * 16 + l15) * 32 + fcol];
#pragma unroll
    for (int ni = 0; ni < 4; ni++)
      bfr[ni][0] = *(const bf16x8*)&Bs[b2][(wn * 64 + ni * 16 + l15) * 32 + fcol];
    stKh(bn2, 0, kn);
    __builtin_amdgcn_s_barrier();
    LGKM0();
    __builtin_amdgcn_s_setprio(1);
#pragma unroll
    for (int mi = 0; mi < 4; mi++)
#pragma unroll
      for (int ni = 0; ni < 4; ni++)
        acc[mi][ni] = mfma16(af[mi], bfr[ni][0], acc[mi][ni]);
    __builtin_amdgcn_s_setprio(0);
    VMW4();  // Kh1(t) landed -> s1 reads safe
    __builtin_amdgcn_s_barrier();

    // ---- P1: lo rows x s1 ----
#pragma unroll
    for (int mi = 0; mi < 4; mi++)
      af[mi] = *(const bf16x8*)&As[b2][8192 + (wm * 128 + mi * 16 + l15) * 32 + fcol];
#pragma unroll
    for (int ni = 0; ni < 4; ni++)
      bfr[ni][1] = *(const bf16x8*)&Bs[b2][8192 + (wn * 64 + ni * 16 + l15) * 32 + fcol];
    stKh(bn2, 1, kn);
    __builtin_amdgcn_s_barrier();
    LGKM0();
    __builtin_amdgcn_s_setprio(1);
#pragma unroll
    for (int mi = 0; mi < 4; mi++)
#pragma unroll
      for (int ni = 0; ni < 4; ni++)
        acc[mi][ni] = mfma16(af[mi], bfr[ni][1], acc[mi][ni]);
    __builtin_amdgcn_s_setprio(0);
    __builtin_amdgcn_s_barrier();

    // ---- P2: hi rows x s0 (B-frags reused from registers) ----
#pragma unroll
    for (int mi = 0; mi < 4; mi++)
      af[mi] = *(const bf16x8*)&As[b2][(wm * 128 + 64 + mi * 16 + l15) * 32 + fcol];
    __builtin_amdgcn_s_barrier();
    LGKM0();
    __builtin_amdgcn_s_setprio(1);
#pragma unroll
    for (int mi = 0; mi < 4; mi++)
#pragma unroll
      for (int ni = 0; ni < 4; ni++)
        acc[mi + 4][ni] = mfma16(af[mi], bfr[ni][0], acc[mi + 4][ni]);
    __builtin_amdgcn_s_setprio(0);
    __builtin_amdgcn_s_barrier();

    // ---- P3: hi rows x s1 ----
#pragma unroll
    for (int mi = 0; mi < 4; mi++)
      af[mi] = *(const bf16x8*)&As[b2][8192 + (wm * 128 + 64 + mi * 16 + l15) * 32 + fcol];
    __builtin_amdgcn_s_barrier();
    LGKM0();
    __builtin_amdgcn_s_setprio(1);
#pragma unroll
    for (int mi = 0; mi < 4; mi++)
#pragma unroll
      for (int ni = 0; ni < 4; ni++)
        acc[mi + 4][ni] = mfma16(af[mi], bfr[ni][1], acc[mi + 4][ni]);
    __builtin_amdgcn_s_setprio(0);
    VMW4();  // Kh0(t+1) landed -> next P0 reads safe
    __builtin_amdgcn_s_barrier();
  }

  // epilogue: C/D layout col=l15, row=quad*4+r
#pragma unroll
  for (int m8 = 0; m8 < 8; m8++)
#pragma unroll
    for (int ni = 0; ni < 4; ni++) {
      size_t row = (size_t)bm + wm * 128 + (m8 >> 2) * 64 + (m8 & 3) * 16 + quad * 4;
      size_t col = (size_t)bn + wn * 64 + ni * 16 + l15;
#pragma unroll
      for (int r = 0; r < 4; r++)
        Cd[(row + r) * N + col] = acc[m8][ni][r];
    }
  asm volatile("s_waitcnt vmcnt(0)" ::: "memory");  // drain wrap-staged loads
}

// ---------------- split-K reduce: out += part ----------------
__global__ void addf4(float* __restrict__ o, const float* __restrict__ p) {
  int i = blockIdx.x * 256 + threadIdx.x;
  float4 a = ((const float4*)o)[i];
  const float4 b = ((const float4*)p)[i];
  a.x += b.x; a.y += b.y; a.z += b.z; a.w += b.w;
  ((float4*)o)[i] = a;
}

// ---------------- RoPE + scatter ----------------
__global__ void rope_scatter(const float* __restrict__ qkv, bf16_t* __restrict__ Qb,
                             bf16_t* __restrict__ Kb, bf16_t* __restrict__ Vt,
                             float* __restrict__ kOut, float* __restrict__ vOut) {
  int idx = blockIdx.x * 256 + threadIdx.x;
  int t = idx / 3072;
  int p = idx - t * 3072;
  const float NEG_L2T_64 = -0.20762050593046f;  // -log2(10000)/64
  const float SS = 0.08838834764831845f * 1.4426950408889634f;  // SCALE*log2(e)
  if (p < 2048) {  // Q
    int hh = p >> 6, pr = p & 63;
    int d0 = pr << 1;
    const float* src = qkv + (size_t)t * QKVN + hh * HD + d0;
    float a = src[0], b = src[1];
    int j0 = d0 & 63, j1 = (d0 + 1) & 63;
    float th0 = (float)t * exp2f((float)j0 * NEG_L2T_64);
    float th1 = (float)t * exp2f((float)j1 * NEG_L2T_64);
    float o0 = (a * cosf(th0) - b * sinf(th0)) * SS;
    float o1 = (b * cosf(th1) + a * sinf(th1)) * SS;
    bf16_t* dst = Qb + ((size_t)hh * SEQ + t) * HD + d0;
    dst[0] = (bf16_t)o0;
    dst[1] = (bf16_t)o1;
  } else if (p < 2560) {  // K
    int q2 = p - 2048;
    int kh = q2 >> 6, pr = q2 & 63;
    int d0 = pr << 1;
    const float* src = qkv + (size_t)t * QKVN + 4096 + kh * HD + d0;
    float a = src[0], b = src[1];
    int j0 = d0 & 63, j1 = (d0 + 1) & 63;
    float th0 = (float)t * exp2f((float)j0 * NEG_L2T_64);
    float th1 = (float)t * exp2f((float)j1 * NEG_L2T_64);
    float o0 = a * cosf(th0) - b * sinf(th0);
    float o1 = b * cosf(th1) + a * sinf(th1);
    bf16_t* dst = Kb + ((size_t)kh * SEQ + t) * HD + d0;
    dst[0] = (bf16_t)o0;
    dst[1] = (bf16_t)o1;
#pragma unroll
    for (int rep = 0; rep < 4; rep++) {
      float* kp = kOut + ((size_t)(kh * 4 + rep) * SEQ + t) * HD + d0;
      kp[0] = o0;
      kp[1] = o1;
    }
  } else {  // V
    int q2 = p - 2560;
    int kh = q2 >> 6, pr = q2 & 63;
    int d0 = pr << 1;
    const float* src = qkv + (size_t)t * QKVN + 5120 + kh * HD + d0;
    float a = src[0], b = src[1];
#pragma unroll
    for (int rep = 0; rep < 4; rep++) {
      float* vp = vOut + ((size_t)(kh * 4 + rep) * SEQ + t) * HD + d0;
      vp[0] = a;
      vp[1] = b;
    }
    // permuted key position for attention's PV slot ordering
    int tp = (t & ~31) + ((t & 12) << 1) + (t & 3) + ((t & 16) >> 2);
    Vt[((size_t)kh * HD + d0) * SEQ + tp] = (bf16_t)a;
    Vt[((size_t)kh * HD + d0 + 1) * SEQ + tp] = (bf16_t)b;
  }
}

// ---------------- Flash attention ----------------
__global__ __launch_bounds__(512, 2) void attn_kernel(const bf16_t* __restrict__ Qb,
                                                      const bf16_t* __restrict__ Kb,
                                                      const bf16_t* __restrict__ Vt,
                                                      bf16_t* __restrict__ AO) {
  __shared__ bf16_t Ks[2][8192];  // [buf][kc(4)][key(64)][d(32)]
  __shared__ bf16_t Vs[2][8192];  // [buf][kt(2)][d(128)][slot(32)]
  const int h = blockIdx.y, kh = h >> 2;
  const int qbase = blockIdx.x * 256;
  const int w = threadIdx.x >> 6, lane = threadIdx.x & 63;
  const int l15 = lane & 15, quad = lane >> 4;
  const bf16_t* KbH = Kb + (size_t)kh * SEQ * HD;
  const bf16_t* VtH = Vt + (size_t)kh * HD * SEQ;

  bf16x8 qf[2][4];
#pragma unroll
  for (int nq = 0; nq < 2; nq++) {
    const bf16_t* qp = Qb + ((size_t)h * SEQ + qbase + w * 32 + nq * 16 + l15) * HD + quad * 8;
#pragma unroll
    for (int kc = 0; kc < 4; kc++) qf[nq][kc] = *(const bf16x8*)(qp + kc * 32);
  }

  f32x4 acc[8][2] = {};
  float rsum[2] = {0.f, 0.f};

  auto stage = [&](int buf, int kt0) {
    if (w < 4) {
      int kc = w;
#pragma unroll
      for (int kg = 0; kg < 4; kg++) {
        const bf16_t* g = KbH + (size_t)(kt0 + kg * 16 + (lane >> 2)) * HD + kc * 32 + (lane & 3) * 8;
        async16(g, &Ks[buf][kc * 2048 + kg * 512]);
      }
    } else {
      int vi = w - 4, kt = vi >> 1, dg0 = (vi & 1) * 4;
#pragma unroll
      for (int j = 0; j < 4; j++) {
        int dg = dg0 + j;
        const bf16_t* g = VtH + (size_t)(dg * 16 + (lane >> 2)) * SEQ + kt0 + kt * 32 + (lane & 3) * 8;
        async16(g, &Vs[buf][kt * 4096 + dg * 512]);
      }
    }
  };

  stage(0, 0);
  int buf = 0;

  for (int kt0 = 0; kt0 < SEQ; kt0 += 64, buf ^= 1) {
    __syncthreads();
    if (kt0 + 64 < SEQ) stage(buf ^ 1, kt0 + 64);

    f32x4 sacc[4][2] = {};
#pragma unroll
    for (int mi = 0; mi < 4; mi++)
#pragma unroll
      for (int kc = 0; kc < 4; kc++) {
        bf16x8 kf = *(const bf16x8*)(&Ks[buf][(kc * 64 + mi * 16 + l15) * 32 + quad * 8]);
#pragma unroll
        for (int nq = 0; nq < 2; nq++)
          sacc[mi][nq] = mfma16(kf, qf[nq][kc], sacc[mi][nq]);
      }

    int pk[4][2][2];
#pragma unroll
    for (int mi = 0; mi < 4; mi++)
#pragma unroll
      for (int nq = 0; nq < 2; nq++) {
        float p0 = exp2f(sacc[mi][nq][0]);
        float p1 = exp2f(sacc[mi][nq][1]);
        float p2 = exp2f(sacc[mi][nq][2]);
        float p3 = exp2f(sacc[mi][nq][3]);
        rsum[nq] += (p0 + p1) + (p2 + p3);
        pk[mi][nq][0] = pack2(p0, p1);
        pk[mi][nq][1] = pack2(p2, p3);
      }

#pragma unroll
    for (int kt = 0; kt < 2; kt++) {
#pragma unroll
      for (int nq = 0; nq < 2; nq++) {
        int4v dw;
        dw[0] = pk[2 * kt][nq][0];
        dw[1] = pk[2 * kt][nq][1];
        dw[2] = pk[2 * kt + 1][nq][0];
        dw[3] = pk[2 * kt + 1][nq][1];
        bf16x8 pf = __builtin_bit_cast(bf16x8, dw);
#pragma unroll
        for (int dt = 0; dt < 8; dt++) {
          bf16x8 vf = *(const bf16x8*)(&Vs[buf][(kt * 128 + dt * 16 + l15) * 32 + quad * 8]);
          acc[dt][nq] = mfma16(vf, pf, acc[dt][nq]);
        }
      }
    }
  }

#pragma unroll
  for (int nq = 0; nq < 2; nq++) {
    float rs = rsum[nq];
    rs += __shfl_xor(rs, 16);
    rs += __shfl_xor(rs, 32);
    float inv = 1.0f / rs;
    int q = qbase + w * 32 + nq * 16 + l15;
#pragma unroll
    for (int dt = 0; dt < 8; dt++) {
      bf16x4 o = { (bf16_t)(acc[dt][nq][0] * inv), (bf16_t)(acc[dt][nq][1] * inv),
                   (bf16_t)(acc[dt][nq][2] * inv), (bf16_t)(acc[dt][nq][3] * inv) };
      *(bf16x4*)(AO + (size_t)q * DIM + h * HD + dt * 16 + quad * 4) = o;
    }
  }
}

extern "C" void kernel_launch(void* const* d_in, const int* in_sizes, int n_in,
                              void* d_out, int out_size, void* d_ws, size_t ws_size,
                              hipStream_t stream) {
  const float* x = (const float*)d_in[0];
  const float* wq = (const float*)d_in[1];
  const float* wk = (const float*)d_in[2];
  const float* wv = (const float*)d_in[3];
  const float* wo = (const float*)d_in[4];
  float* out = (float*)d_out;
  float* kOut = out + (size_t)SEQ * DIM;
  float* vOut = kOut + (size_t)NH * SEQ * HD;

  char* ws = (char*)d_ws;
  bf16_t* Xb = (bf16_t*)ws;                          // 16 MB; later aliased as AO
  bf16_t* WT = (bf16_t*)(ws + 16777216);             // 48 MB: [wq^T|wk^T|wv^T]
  float* Cp1 = (float*)(ws + 16777216);              // alias: split-K partial (WT dead)
  float* QKV = (float*)(ws + 67108864);              // 48 MB fp32
  bf16_t* WoT = (bf16_t*)(ws + 67108864);            // alias (QKV dead by then)
  bf16_t* Qb = (bf16_t*)(ws + 117440512);            // 16 MB
  bf16_t* Kb = (bf16_t*)(ws + 134217728);            // 4 MB
  bf16_t* Vt = (bf16_t*)(ws + 138412032);            // 4 MB (slot-permuted keys)
  bf16_t* AO = Xb;

  dim3 tb(32, 8);
  cast_x<<<8192, 256, 0, stream>>>(x, Xb);
  tcast<<<dim3(128, 128), tb, 0, stream>>>(wq, WT, 4096, 4096);
  tcast<<<dim3(32, 128), tb, 0, stream>>>(wk, WT + (size_t)4096 * 4096, 1024, 4096);
  tcast<<<dim3(32, 128), tb, 0, stream>>>(wv, WT + (size_t)5120 * 4096, 1024, 4096);
  gemm256<<<dim3(24, 8, 1), 512, 0, stream>>>(Xb, WT, QKV, nullptr, 2048, 6144, 4096, 4096);
  rope_scatter<<<24576, 256, 0, stream>>>(QKV, Qb, Kb, Vt, kOut, vOut);
  tcast<<<dim3(128, 128), tb, 0, stream>>>(wo, WoT, 4096, 4096);
  attn_kernel<<<dim3(8, 32), 512, 0, stream>>>(Qb, Kb, Vt, AO);
  gemm256<<<dim3(16, 8, 2), 512, 0, stream>>>(AO, WoT, out, Cp1, 2048, 4096, 4096, 2048);
  addf4<<<8192, 256, 0, stream>>>(out, Cp1);
}

// Round 5
// 577.955 us; speedup vs baseline: 1.0014x; 1.0014x over previous
//
#include <hip/hip_runtime.h>
#include <cstdint>
#include <cstddef>

#define DIM 4096
#define SEQ 2048
#define NH 32
#define NKV 8
#define HD 128
#define QKVN 6144

typedef __bf16 bf16_t;
typedef __bf16 bf16x8 __attribute__((ext_vector_type(8)));
typedef __bf16 bf16x4 __attribute__((ext_vector_type(4)));
typedef __bf16 bf16x2 __attribute__((ext_vector_type(2)));
typedef float f32x4 __attribute__((ext_vector_type(4)));
typedef int int4v __attribute__((ext_vector_type(4)));

__device__ __forceinline__ f32x4 mfma16(bf16x8 a, bf16x8 b, f32x4 c) {
  return __builtin_amdgcn_mfma_f32_16x16x32_bf16(a, b, c, 0, 0, 0);
}

__device__ __forceinline__ void async16(const bf16_t* g, bf16_t* l) {
  __builtin_amdgcn_global_load_lds((__attribute__((address_space(1))) void*)g,
                                   (__attribute__((address_space(3))) void*)l,
                                   16, 0, 0);
}

__device__ __forceinline__ int pack2(float a, float b) {
  bf16x2 h = { (bf16_t)a, (bf16_t)b };
  return __builtin_bit_cast(int, h);
}

// rule #18: inline-asm waits must be followed by sched_barrier(0)
#define LGKM0() do { asm volatile("s_waitcnt lgkmcnt(0)" ::: "memory"); \
                     __builtin_amdgcn_sched_barrier(0); } while (0)

template <int N> __device__ __forceinline__ void vmw() {
  if constexpr (N == 2) asm volatile("s_waitcnt vmcnt(2)" ::: "memory");
  else if constexpr (N == 8) asm volatile("s_waitcnt vmcnt(8)" ::: "memory");
  __builtin_amdgcn_sched_barrier(0);
}

// ---------------- cast x (fp32 -> bf16), 4 elems/thread ----------------
__global__ void cast_x(const float* __restrict__ x, bf16_t* __restrict__ xb) {
  int i = blockIdx.x * 256 + threadIdx.x;
  const float4 v = ((const float4*)x)[i];
  bf16x4 o = { (bf16_t)v.x, (bf16_t)v.y, (bf16_t)v.z, (bf16_t)v.w };
  *(bf16x4*)(xb + (size_t)i * 4) = o;
}

// ------- transpose-cast: src fp32 (Kdim x Ncols) -> dst bf16 (Ncols x Kdim) -------
__global__ void tcast(const float* __restrict__ src, bf16_t* __restrict__ dst,
                      int Ncols, int Kdim) {
  __shared__ float tile[32][33];
  int n0 = blockIdx.x * 32, k0 = blockIdx.y * 32;
  int tx = threadIdx.x, ty = threadIdx.y;  // 32 x 8
#pragma unroll
  for (int r = 0; r < 4; r++)
    tile[ty + 8 * r][tx] = src[(size_t)(k0 + ty + 8 * r) * Ncols + n0 + tx];
  __syncthreads();
#pragma unroll
  for (int r = 0; r < 4; r++)
    dst[(size_t)(n0 + ty + 8 * r) * Kdim + k0 + tx] = (bf16_t)tile[tx][ty + 8 * r];
}

// ---------------- GEMM: 256x256 tile, BK=64, wave tile 128x64 ----------------
// C = A @ Bt^T.  LDS [buf][256 rows][64 cols] (row = 128 B = full 32-bank span),
// 8-slot XOR swizzle: LDS 16B-group g at row r holds global group g^(r&7)
// (HW-verified 0 conflicts in this layout).  4 uniform 16-MFMA phases/K-tile:
// {lo x s0, lo x s1, hi x s0, hi x s1} (s = column half); ds_reads 8/8/4/4,
// B-frags (both halves) register-resident across the tile.
// Staging granule = 64 rows (8 KB, one async16/thread).  Tile t's P0 issues all
// 8 granules of t+1 in order {A-lo0, A-lo1, B0..B3, A-hi0, A-hi1}:
//   first 6 deadline next-P0  -> vmcnt(2) at P3-end (issued 4 phases earlier)
//   last 2  deadline P2       -> vmcnt(8) at P1-end (10 in flight, keep 8)
// In-flight never < 2; no drain-to-0 in the main loop.
// Split-K via blockIdx.z (partial into Cp, reduced by addf4).
__global__ __launch_bounds__(512) void gemm256(const bf16_t* __restrict__ A,
                                               const bf16_t* __restrict__ Bt,
                                               float* __restrict__ C,
                                               float* __restrict__ Cp,
                                               int M, int N, int K, int Kloc) {
  __shared__ bf16_t As[2][16384];  // [buf][row*64 + col]
  __shared__ bf16_t Bs[2][16384];
  const int t = threadIdx.x;
  const int lane = t & 63;
  const int l15 = lane & 15, quad = lane >> 4;
  const int w = t >> 6, wm = w >> 2, wn = w & 3;  // 2 x 4 wave grid

  // bijective XCD swizzle (nwg % 8 == 0 both call sites)
  const int gx = gridDim.x;
  const int nwg = gx * gridDim.y;
  const int id = blockIdx.y * gx + blockIdx.x;
  const int swz = (id & 7) * (nwg >> 3) + (id >> 3);
  const int bm = (swz / gx) * 256, bn = (swz % gx) * 256;
  const int kbase = blockIdx.z * Kloc;
  float* __restrict__ Cd = blockIdx.z ? Cp : C;

  // staging: thread t -> row t>>3 (8 threads/row, 16B each), LDS group t&7
  // holds global group (t&7)^(row&7)  (self-inverse swizzle)
  const int srow = t >> 3;
  const int scol = ((t & 7) ^ (srow & 7)) << 3;
  const bf16_t* gA = A + (size_t)(bm + srow) * K + kbase + scol;
  const bf16_t* gB = Bt + (size_t)(bn + srow) * K + kbase + scol;
  const int ldst = t * 8;

  // fragment read: global group G = s*4+quad -> LDS group G^(l15&7)
  const int g0 = ((quad ^ (l15 & 7)) << 3);        // s0
  const int g1 = (((4 | quad) ^ (l15 & 7)) << 3);  // s1

  f32x4 acc[8][4] = {};
  bf16x8 af[4], bfr[4][2];

  // issue order: {A-lo(wm0), A-lo(wm1), B0..B3, A-hi(wm0), A-hi(wm1)}
  auto stage = [&](int b2, int kk) {
    async16(gA + kk, &As[b2][ldst]);                         // A rows 0-63
    async16(gA + (size_t)128 * K + kk, &As[b2][8192 + ldst]); // A rows 128-191
    async16(gB + kk, &Bs[b2][ldst]);                          // B0
    async16(gB + (size_t)64 * K + kk, &Bs[b2][4096 + ldst]);  // B1
    async16(gB + (size_t)128 * K + kk, &Bs[b2][8192 + ldst]); // B2
    async16(gB + (size_t)192 * K + kk, &Bs[b2][12288 + ldst]);// B3
    async16(gA + (size_t)64 * K + kk, &As[b2][4096 + ldst]);  // A rows 64-127
    async16(gA + (size_t)192 * K + kk, &As[b2][12288 + ldst]);// A rows 192-255
  };

  // prologue: stage tile 0; first 6 needed at P0, hi-granules stay in flight
  stage(0, 0);
  vmw<2>();
  __builtin_amdgcn_s_barrier();

  const int nkt = Kloc >> 6;
  for (int kt = 0; kt < nkt; ++kt) {
    const int b2 = kt & 1, bn2 = b2 ^ 1;
    const int kn = (kt + 1 == nkt) ? 0 : (kt + 1) << 6;  // wrap-stage dead tail

    // ---- P0: lo rows x s0 ; issue all 8 granules of t+1 ----
#pragma unroll
    for (int mi = 0; mi < 4; mi++)
      af[mi] = *(const bf16x8*)&As[b2][(wm * 128 + mi * 16 + l15) * 64 + g0];
#pragma unroll
    for (int ni = 0; ni < 4; ni++) {
      bfr[ni][0] = *(const bf16x8*)&Bs[b2][(wn * 64 + ni * 16 + l15) * 64 + g0];
      bfr[ni][1] = *(const bf16x8*)&Bs[b2][(wn * 64 + ni * 16 + l15) * 64 + g1];
    }
    stage(bn2, kn);
    __builtin_amdgcn_s_barrier();
    LGKM0();
    __builtin_amdgcn_s_setprio(1);
#pragma unroll
    for (int mi = 0; mi < 4; mi++)
#pragma unroll
      for (int ni = 0; ni < 4; ni++)
        acc[mi][ni] = mfma16(af[mi], bfr[ni][0], acc[mi][ni]);
    __builtin_amdgcn_s_setprio(0);
    __builtin_amdgcn_s_barrier();

    // ---- P1: lo rows x s1 ----
#pragma unroll
    for (int mi = 0; mi < 4; mi++)
      af[mi] = *(const bf16x8*)&As[b2][(wm * 128 + mi * 16 + l15) * 64 + g1];
    __builtin_amdgcn_s_barrier();
    LGKM0();
    __builtin_amdgcn_s_setprio(1);
#pragma unroll
    for (int mi = 0; mi < 4; mi++)
#pragma unroll
      for (int ni = 0; ni < 4; ni++)
        acc[mi][ni] = mfma16(af[mi], bfr[ni][1], acc[mi][ni]);
    __builtin_amdgcn_s_setprio(0);
    vmw<8>();  // retire this tile's hi-granules (gates P2 reads)
    __builtin_amdgcn_s_barrier();

    // ---- P2: hi rows x s0 (B-frags from registers) ----
#pragma unroll
    for (int mi = 0; mi < 4; mi++)
      af[mi] = *(const bf16x8*)&As[b2][(wm * 128 + 64 + mi * 16 + l15) * 64 + g0];
    __builtin_amdgcn_s_barrier();
    LGKM0();
    __builtin_amdgcn_s_setprio(1);
#pragma unroll
    for (int mi = 0; mi < 4; mi++)
#pragma unroll
      for (int ni = 0; ni < 4; ni++)
        acc[mi + 4][ni] = mfma16(af[mi], bfr[ni][0], acc[mi + 4][ni]);
    __builtin_amdgcn_s_setprio(0);
    __builtin_amdgcn_s_barrier();

    // ---- P3: hi rows x s1 ----
#pragma unroll
    for (int mi = 0; mi < 4; mi++)
      af[mi] = *(const bf16x8*)&As[b2][(wm * 128 + 64 + mi * 16 + l15) * 64 + g1];
    __builtin_amdgcn_s_barrier();
    LGKM0();
    __builtin_amdgcn_s_setprio(1);
#pragma unroll
    for (int mi = 0; mi < 4; mi++)
#pragma unroll
      for (int ni = 0; ni < 4; ni++)
        acc[mi + 4][ni] = mfma16(af[mi], bfr[ni][1], acc[mi + 4][ni]);
    __builtin_amdgcn_s_setprio(0);
    vmw<2>();  // retire t+1's lo+B granules (gates next P0 reads)
    __builtin_amdgcn_s_barrier();
  }

  // epilogue: C/D layout col=l15, row=quad*4+r
#pragma unroll
  for (int m8 = 0; m8 < 8; m8++)
#pragma unroll
    for (int ni = 0; ni < 4; ni++) {
      size_t row = (size_t)bm + wm * 128 + (m8 >> 2) * 64 + (m8 & 3) * 16 + quad * 4;
      size_t col = (size_t)bn + wn * 64 + ni * 16 + l15;
#pragma unroll
      for (int r = 0; r < 4; r++)
        Cd[(row + r) * N + col] = acc[m8][ni][r];
    }
  asm volatile("s_waitcnt vmcnt(0)" ::: "memory");  // drain wrap-staged loads
}

// ---------------- split-K reduce: out += part ----------------
__global__ void addf4(float* __restrict__ o, const float* __restrict__ p) {
  int i = blockIdx.x * 256 + threadIdx.x;
  float4 a = ((const float4*)o)[i];
  const float4 b = ((const float4*)p)[i];
  a.x += b.x; a.y += b.y; a.z += b.z; a.w += b.w;
  ((float4*)o)[i] = a;
}

// ---------------- RoPE + scatter ----------------
__global__ void rope_scatter(const float* __restrict__ qkv, bf16_t* __restrict__ Qb,
                             bf16_t* __restrict__ Kb, bf16_t* __restrict__ Vt,
                             float* __restrict__ kOut, float* __restrict__ vOut) {
  int idx = blockIdx.x * 256 + threadIdx.x;
  int t = idx / 3072;
  int p = idx - t * 3072;
  const float NEG_L2T_64 = -0.20762050593046f;  // -log2(10000)/64
  const float SS = 0.08838834764831845f * 1.4426950408889634f;  // SCALE*log2(e)
  if (p < 2048) {  // Q
    int hh = p >> 6, pr = p & 63;
    int d0 = pr << 1;
    const float* src = qkv + (size_t)t * QKVN + hh * HD + d0;
    float a = src[0], b = src[1];
    int j0 = d0 & 63, j1 = (d0 + 1) & 63;
    float th0 = (float)t * exp2f((float)j0 * NEG_L2T_64);
    float th1 = (float)t * exp2f((float)j1 * NEG_L2T_64);
    float o0 = (a * cosf(th0) - b * sinf(th0)) * SS;
    float o1 = (b * cosf(th1) + a * sinf(th1)) * SS;
    bf16_t* dst = Qb + ((size_t)hh * SEQ + t) * HD + d0;
    dst[0] = (bf16_t)o0;
    dst[1] = (bf16_t)o1;
  } else if (p < 2560) {  // K
    int q2 = p - 2048;
    int kh = q2 >> 6, pr = q2 & 63;
    int d0 = pr << 1;
    const float* src = qkv + (size_t)t * QKVN + 4096 + kh * HD + d0;
    float a = src[0], b = src[1];
    int j0 = d0 & 63, j1 = (d0 + 1) & 63;
    float th0 = (float)t * exp2f((float)j0 * NEG_L2T_64);
    float th1 = (float)t * exp2f((float)j1 * NEG_L2T_64);
    float o0 = a * cosf(th0) - b * sinf(th0);
    float o1 = b * cosf(th1) + a * sinf(th1);
    bf16_t* dst = Kb + ((size_t)kh * SEQ + t) * HD + d0;
    dst[0] = (bf16_t)o0;
    dst[1] = (bf16_t)o1;
#pragma unroll
    for (int rep = 0; rep < 4; rep++) {
      float* kp = kOut + ((size_t)(kh * 4 + rep) * SEQ + t) * HD + d0;
      kp[0] = o0;
      kp[1] = o1;
    }
  } else {  // V
    int q2 = p - 2560;
    int kh = q2 >> 6, pr = q2 & 63;
    int d0 = pr << 1;
    const float* src = qkv + (size_t)t * QKVN + 5120 + kh * HD + d0;
    float a = src[0], b = src[1];
#pragma unroll
    for (int rep = 0; rep < 4; rep++) {
      float* vp = vOut + ((size_t)(kh * 4 + rep) * SEQ + t) * HD + d0;
      vp[0] = a;
      vp[1] = b;
    }
    // permuted key position for attention's PV slot ordering
    int tp = (t & ~31) + ((t & 12) << 1) + (t & 3) + ((t & 16) >> 2);
    Vt[((size_t)kh * HD + d0) * SEQ + tp] = (bf16_t)a;
    Vt[((size_t)kh * HD + d0 + 1) * SEQ + tp] = (bf16_t)b;
  }
}

// ---------------- Flash attention ----------------
__global__ __launch_bounds__(512, 2) void attn_kernel(const bf16_t* __restrict__ Qb,
                                                      const bf16_t* __restrict__ Kb,
                                                      const bf16_t* __restrict__ Vt,
                                                      bf16_t* __restrict__ AO) {
  __shared__ bf16_t Ks[2][8192];  // [buf][kc(4)][key(64)][d(32)]
  __shared__ bf16_t Vs[2][8192];  // [buf][kt(2)][d(128)][slot(32)]
  const int h = blockIdx.y, kh = h >> 2;
  const int qbase = blockIdx.x * 256;
  const int w = threadIdx.x >> 6, lane = threadIdx.x & 63;
  const int l15 = lane & 15, quad = lane >> 4;
  const bf16_t* KbH = Kb + (size_t)kh * SEQ * HD;
  const bf16_t* VtH = Vt + (size_t)kh * HD * SEQ;

  bf16x8 qf[2][4];
#pragma unroll
  for (int nq = 0; nq < 2; nq++) {
    const bf16_t* qp = Qb + ((size_t)h * SEQ + qbase + w * 32 + nq * 16 + l15) * HD + quad * 8;
#pragma unroll
    for (int kc = 0; kc < 4; kc++) qf[nq][kc] = *(const bf16x8*)(qp + kc * 32);
  }

  f32x4 acc[8][2] = {};
  float rsum[2] = {0.f, 0.f};

  auto stage = [&](int buf, int kt0) {
    if (w < 4) {
      int kc = w;
#pragma unroll
      for (int kg = 0; kg < 4; kg++) {
        const bf16_t* g = KbH + (size_t)(kt0 + kg * 16 + (lane >> 2)) * HD + kc * 32 + (lane & 3) * 8;
        async16(g, &Ks[buf][kc * 2048 + kg * 512]);
      }
    } else {
      int vi = w - 4, kt = vi >> 1, dg0 = (vi & 1) * 4;
#pragma unroll
      for (int j = 0; j < 4; j++) {
        int dg = dg0 + j;
        const bf16_t* g = VtH + (size_t)(dg * 16 + (lane >> 2)) * SEQ + kt0 + kt * 32 + (lane & 3) * 8;
        async16(g, &Vs[buf][kt * 4096 + dg * 512]);
      }
    }
  };

  stage(0, 0);
  int buf = 0;

  for (int kt0 = 0; kt0 < SEQ; kt0 += 64, buf ^= 1) {
    __syncthreads();
    if (kt0 + 64 < SEQ) stage(buf ^ 1, kt0 + 64);

    f32x4 sacc[4][2] = {};
#pragma unroll
    for (int mi = 0; mi < 4; mi++)
#pragma unroll
      for (int kc = 0; kc < 4; kc++) {
        bf16x8 kf = *(const bf16x8*)(&Ks[buf][(kc * 64 + mi * 16 + l15) * 32 + quad * 8]);
#pragma unroll
        for (int nq = 0; nq < 2; nq++)
          sacc[mi][nq] = mfma16(kf, qf[nq][kc], sacc[mi][nq]);
      }

    int pk[4][2][2];
#pragma unroll
    for (int mi = 0; mi < 4; mi++)
#pragma unroll
      for (int nq = 0; nq < 2; nq++) {
        float p0 = exp2f(sacc[mi][nq][0]);
        float p1 = exp2f(sacc[mi][nq][1]);
        float p2 = exp2f(sacc[mi][nq][2]);
        float p3 = exp2f(sacc[mi][nq][3]);
        rsum[nq] += (p0 + p1) + (p2 + p3);
        pk[mi][nq][0] = pack2(p0, p1);
        pk[mi][nq][1] = pack2(p2, p3);
      }

#pragma unroll
    for (int kt = 0; kt < 2; kt++) {
#pragma unroll
      for (int nq = 0; nq < 2; nq++) {
        int4v dw;
        dw[0] = pk[2 * kt][nq][0];
        dw[1] = pk[2 * kt][nq][1];
        dw[2] = pk[2 * kt + 1][nq][0];
        dw[3] = pk[2 * kt + 1][nq][1];
        bf16x8 pf = __builtin_bit_cast(bf16x8, dw);
#pragma unroll
        for (int dt = 0; dt < 8; dt++) {
          bf16x8 vf = *(const bf16x8*)(&Vs[buf][(kt * 128 + dt * 16 + l15) * 32 + quad * 8]);
          acc[dt][nq] = mfma16(vf, pf, acc[dt][nq]);
        }
      }
    }
  }

#pragma unroll
  for (int nq = 0; nq < 2; nq++) {
    float rs = rsum[nq];
    rs += __shfl_xor(rs, 16);
    rs += __shfl_xor(rs, 32);
    float inv = 1.0f / rs;
    int q = qbase + w * 32 + nq * 16 + l15;
#pragma unroll
    for (int dt = 0; dt < 8; dt++) {
      bf16x4 o = { (bf16_t)(acc[dt][nq][0] * inv), (bf16_t)(acc[dt][nq][1] * inv),
                   (bf16_t)(acc[dt][nq][2] * inv), (bf16_t)(acc[dt][nq][3] * inv) };
      *(bf16x4*)(AO + (size_t)q * DIM + h * HD + dt * 16 + quad * 4) = o;
    }
  }
}

extern "C" void kernel_launch(void* const* d_in, const int* in_sizes, int n_in,
                              void* d_out, int out_size, void* d_ws, size_t ws_size,
                              hipStream_t stream) {
  const float* x = (const float*)d_in[0];
  const float* wq = (const float*)d_in[1];
  const float* wk = (const float*)d_in[2];
  const float* wv = (const float*)d_in[3];
  const float* wo = (const float*)d_in[4];
  float* out = (float*)d_out;
  float* kOut = out + (size_t)SEQ * DIM;
  float* vOut = kOut + (size_t)NH * SEQ * HD;

  char* ws = (char*)d_ws;
  bf16_t* Xb = (bf16_t*)ws;                          // 16 MB; later aliased as AO
  bf16_t* WT = (bf16_t*)(ws + 16777216);             // 48 MB: [wq^T|wk^T|wv^T]
  float* Cp1 = (float*)(ws + 16777216);              // alias: split-K partial (WT dead)
  float* QKV = (float*)(ws + 67108864);              // 48 MB fp32
  bf16_t* WoT = (bf16_t*)(ws + 67108864);            // alias (QKV dead by then)
  bf16_t* Qb = (bf16_t*)(ws + 117440512);            // 16 MB
  bf16_t* Kb = (bf16_t*)(ws + 134217728);            // 4 MB
  bf16_t* Vt = (bf16_t*)(ws + 138412032);            // 4 MB (slot-permuted keys)
  bf16_t* AO = Xb;

  dim3 tb(32, 8);
  cast_x<<<8192, 256, 0, stream>>>(x, Xb);
  tcast<<<dim3(128, 128), tb, 0, stream>>>(wq, WT, 4096, 4096);
  tcast<<<dim3(32, 128), tb, 0, stream>>>(wk, WT + (size_t)4096 * 4096, 1024, 4096);
  tcast<<<dim3(32, 128), tb, 0, stream>>>(wv, WT + (size_t)5120 * 4096, 1024, 4096);
  gemm256<<<dim3(24, 8, 1), 512, 0, stream>>>(Xb, WT, QKV, nullptr, 2048, 6144, 4096, 4096);
  rope_scatter<<<24576, 256, 0, stream>>>(QKV, Qb, Kb, Vt, kOut, vOut);
  tcast<<<dim3(128, 128), tb, 0, stream>>>(wo, WoT, 4096, 4096);
  attn_kernel<<<dim3(8, 32), 512, 0, stream>>>(Qb, Kb, Vt, AO);
  gemm256<<<dim3(16, 8, 2), 512, 0, stream>>>(AO, WoT, out, Cp1, 2048, 4096, 4096, 2048);
  addf4<<<8192, 256, 0, stream>>>(out, Cp1);
}

// Round 6
// 522.505 us; speedup vs baseline: 1.1077x; 1.1061x over previous
//
#include <hip/hip_runtime.h>
#include <cstdint>
#include <cstddef>

#define DIM 4096
#define SEQ 2048
#define NH 32
#define NKV 8
#define HD 128
#define QKVN 6144

typedef __bf16 bf16_t;
typedef __bf16 bf16x8 __attribute__((ext_vector_type(8)));
typedef __bf16 bf16x4 __attribute__((ext_vector_type(4)));
typedef __bf16 bf16x2 __attribute__((ext_vector_type(2)));
typedef float f32x4 __attribute__((ext_vector_type(4)));
typedef int int4v __attribute__((ext_vector_type(4)));

__device__ __forceinline__ f32x4 mfma16(bf16x8 a, bf16x8 b, f32x4 c) {
  return __builtin_amdgcn_mfma_f32_16x16x32_bf16(a, b, c, 0, 0, 0);
}

__device__ __forceinline__ void async16(const bf16_t* g, bf16_t* l) {
  __builtin_amdgcn_global_load_lds((__attribute__((address_space(1))) void*)g,
                                   (__attribute__((address_space(3))) void*)l,
                                   16, 0, 0);
}

__device__ __forceinline__ int pack2(float a, float b) {
  bf16x2 h = { (bf16_t)a, (bf16_t)b };
  return __builtin_bit_cast(int, h);
}

// rule #18: inline-asm waits must be followed by sched_barrier(0)
#define LGKM0() do { asm volatile("s_waitcnt lgkmcnt(0)" ::: "memory"); \
                     __builtin_amdgcn_sched_barrier(0); } while (0)

template <int N> __device__ __forceinline__ void vmw() {
  if constexpr (N == 2) asm volatile("s_waitcnt vmcnt(2)" ::: "memory");
  else if constexpr (N == 3) asm volatile("s_waitcnt vmcnt(3)" ::: "memory");
  else if constexpr (N == 4) asm volatile("s_waitcnt vmcnt(4)" ::: "memory");
  __builtin_amdgcn_sched_barrier(0);
}

// ---------------- cast x (fp32 -> bf16), 4 elems/thread ----------------
__global__ void cast_x(const float* __restrict__ x, bf16_t* __restrict__ xb) {
  int i = blockIdx.x * 256 + threadIdx.x;
  const float4 v = ((const float4*)x)[i];
  bf16x4 o = { (bf16_t)v.x, (bf16_t)v.y, (bf16_t)v.z, (bf16_t)v.w };
  *(bf16x4*)(xb + (size_t)i * 4) = o;
}

// ------- transpose-cast: src fp32 (Kdim x Ncols) -> dst bf16 (Ncols x Kdim) -------
__global__ void tcast(const float* __restrict__ src, bf16_t* __restrict__ dst,
                      int Ncols, int Kdim) {
  __shared__ float tile[32][33];
  int n0 = blockIdx.x * 32, k0 = blockIdx.y * 32;
  int tx = threadIdx.x, ty = threadIdx.y;  // 32 x 8
#pragma unroll
  for (int r = 0; r < 4; r++)
    tile[ty + 8 * r][tx] = src[(size_t)(k0 + ty + 8 * r) * Ncols + n0 + tx];
  __syncthreads();
#pragma unroll
  for (int r = 0; r < 4; r++)
    dst[(size_t)(n0 + ty + 8 * r) * Kdim + k0 + tx] = (bf16_t)tile[tx][ty + 8 * r];
}

// ---------------- GEMM: 256 x (NF*64) tile, BK=64, 8 waves -------------------
// Round-3 structure (best measured: 0 bank conflicts) + m201-style STAGGERED
// staging: tile t+1's granules (64 rows x 64 cols each) are issued spread
// across tile t's phases, BEFORE the phase barrier, into buf^1 (never the
// live buffer).  Issue order == deadline order, so counted vmcnt gates
// (placed before a barrier => collectively valid across waves) retire exact
// FIFO prefixes:
//   NF=3 quotas: P0{A0,A1} P1{B0,B1} P2{A2,A3,B2}; gates end-P0 vmcnt(3),
//                end-P1 vmcnt(4), end-P2 vmcnt(3)
//   NF=2 quotas: P0{A0,A1,B0,B1} P1{A2,A3}; gates end-P0 vmcnt(4),
//                end-P1 vmcnt(2)
// Every issue->gate distance >= 2 phases (~2000 cy > HBM latency); in-flight
// never < 2.  Full (row&7) XOR swizzle (HW-verified 0 conflicts).
// Phase map: P0 = lo-mi x n01 (16 MFMA), P1 = hi-mi x n01, P2(NF3) = all x n2.
template <int NF>
__global__ __launch_bounds__(512) void gemm256(const bf16_t* __restrict__ A,
                                               const bf16_t* __restrict__ Bt,
                                               float* __restrict__ C,
                                               int M, int N, int K) {
  __shared__ bf16_t As[2][16384];
  __shared__ bf16_t Bs[2][NF * 4096];
  const int t = threadIdx.x;
  const int lane = t & 63;
  const int l15 = lane & 15, quad = lane >> 4;
  const int w = t >> 6, wm = w >> 2, wn = w & 3;  // 2 x 4 wave grid
  const int cgx = l15 & 7;

  // bijective XCD swizzle (nwg == 256, %8 == 0): each XCD owns one M-strip.
  const int gx = gridDim.x;
  const int nwg = gx * gridDim.y;
  const int id = blockIdx.y * gx + blockIdx.x;
  const int swz = (id & 7) * (nwg >> 3) + (id >> 3);
  const int bm = (swz / gx) * 256, bn = (swz % gx) * (NF * 64);

  // staging: thread t -> row t>>3 within a 64-row granule; LDS col-group t&7
  // holds global col-group (t&7)^(row&7)  (self-inverse swizzle)
  const int srow = t >> 3;
  const int scol = ((t & 7) ^ (srow & 7)) << 3;
  const bf16_t* gA = A + (size_t)(bm + srow) * K + scol;
  const bf16_t* gB = Bt + (size_t)(bn + srow) * K + scol;
  const int ldst = t * 8;

  f32x4 acc[8][NF] = {};

  // per-phase staging quotas (issue order == deadline order)
  auto stP0 = [&](int b2, int kk) {
    async16(gA + kk, &As[b2][ldst]);                           // A0
    async16(gA + (size_t)64 * K + kk, &As[b2][4096 + ldst]);   // A1
    if constexpr (NF == 2) {
      async16(gB + kk, &Bs[b2][ldst]);                         // B0
      async16(gB + (size_t)64 * K + kk, &Bs[b2][4096 + ldst]); // B1
    }
  };
  auto stP1 = [&](int b2, int kk) {
    if constexpr (NF == 3) {
      async16(gB + kk, &Bs[b2][ldst]);                         // B0
      async16(gB + (size_t)64 * K + kk, &Bs[b2][4096 + ldst]); // B1
    } else {
      async16(gA + (size_t)128 * K + kk, &As[b2][8192 + ldst]);  // A2
      async16(gA + (size_t)192 * K + kk, &As[b2][12288 + ldst]); // A3
    }
  };
  auto stP2 = [&](int b2, int kk) {  // NF==3 only
    async16(gA + (size_t)128 * K + kk, &As[b2][8192 + ldst]);   // A2
    async16(gA + (size_t)192 * K + kk, &As[b2][12288 + ldst]);  // A3
    async16(gB + (size_t)128 * K + kk, &Bs[b2][8192 + ldst]);   // B2
  };

  // prologue: full tile-0 batch in deadline order; gate its P0 granules
  stP0(0, 0);
  stP1(0, 0);
  if constexpr (NF == 3) stP2(0, 0);
  if constexpr (NF == 3) vmw<3>(); else vmw<2>();
  __builtin_amdgcn_s_barrier();

  const int nkt = K >> 6;
  for (int kt = 0; kt < nkt; ++kt) {
    const int b2 = kt & 1, bo = b2 ^ 1;
    const int kn = (kt + 1 == nkt) ? 0 : (kt + 1) << 6;  // wrap-stage dead tail

    bf16x8 afl[4][2], afh[4][2], bf01[2][2], bf2[2];

    // ---- P0: lo-mi x n0,n1 ; stage quota P0 of t+1 into buf^1 ----
#pragma unroll
    for (int mi = 0; mi < 4; mi++)
#pragma unroll
      for (int s = 0; s < 2; s++)
        afl[mi][s] = *(const bf16x8*)&As[b2][(wm * 64 + mi * 16 + l15) * 64 +
                                            ((((s << 2) | quad) ^ cgx) << 3)];
#pragma unroll
    for (int ni = 0; ni < 2; ni++)
#pragma unroll
      for (int s = 0; s < 2; s++)
        bf01[ni][s] = *(const bf16x8*)&Bs[b2][(ni * 64 + wn * 16 + l15) * 64 +
                                              ((((s << 2) | quad) ^ cgx) << 3)];
    stP0(bo, kn);
    __builtin_amdgcn_s_barrier();
    LGKM0();
    __builtin_amdgcn_s_setprio(1);
#pragma unroll
    for (int mi = 0; mi < 4; mi++)
#pragma unroll
      for (int ni = 0; ni < 2; ni++)
#pragma unroll
        for (int s = 0; s < 2; s++)
          acc[mi][ni] = mfma16(afl[mi][s], bf01[ni][s], acc[mi][ni]);
    __builtin_amdgcn_s_setprio(0);
    if constexpr (NF == 3) vmw<3>(); else vmw<4>();  // gates P1's afh reads
    __builtin_amdgcn_s_barrier();

    // ---- P1: hi-mi x n0,n1 ; stage quota P1 ----
#pragma unroll
    for (int mi = 0; mi < 4; mi++)
#pragma unroll
      for (int s = 0; s < 2; s++)
        afh[mi][s] = *(const bf16x8*)&As[b2][(128 + wm * 64 + mi * 16 + l15) * 64 +
                                             ((((s << 2) | quad) ^ cgx) << 3)];
    stP1(bo, kn);
    __builtin_amdgcn_s_barrier();
    LGKM0();
    __builtin_amdgcn_s_setprio(1);
#pragma unroll
    for (int mi = 0; mi < 4; mi++)
#pragma unroll
      for (int ni = 0; ni < 2; ni++)
#pragma unroll
        for (int s = 0; s < 2; s++)
          acc[mi + 4][ni] = mfma16(afh[mi][s], bf01[ni][s], acc[mi + 4][ni]);
    __builtin_amdgcn_s_setprio(0);
    if constexpr (NF == 3) vmw<4>(); else vmw<2>();  // NF3: gates P2's bf2; NF2: gates next P0
    __builtin_amdgcn_s_barrier();

    // ---- P2 (NF==3 only): all-mi x n2 ; stage quota P2 ----
    if constexpr (NF == 3) {
#pragma unroll
      for (int s = 0; s < 2; s++)
        bf2[s] = *(const bf16x8*)&Bs[b2][(128 + wn * 16 + l15) * 64 +
                                         ((((s << 2) | quad) ^ cgx) << 3)];
      stP2(bo, kn);
      __builtin_amdgcn_s_barrier();
      LGKM0();
      __builtin_amdgcn_s_setprio(1);
#pragma unroll
      for (int mi = 0; mi < 4; mi++)
#pragma unroll
        for (int s = 0; s < 2; s++) {
          acc[mi][2] = mfma16(afl[mi][s], bf2[s], acc[mi][2]);
          acc[mi + 4][2] = mfma16(afh[mi][s], bf2[s], acc[mi + 4][2]);
        }
      __builtin_amdgcn_s_setprio(0);
      vmw<3>();  // gates next tile's P0 reads
      __builtin_amdgcn_s_barrier();
    }
  }

  // epilogue: C/D layout col=l15, row=quad*4+r
#pragma unroll
  for (int mi = 0; mi < 8; mi++)
#pragma unroll
    for (int ni = 0; ni < NF; ni++) {
      size_t row = (size_t)bm + (mi >> 2) * 128 + wm * 64 + (mi & 3) * 16 + quad * 4;
      size_t col = (size_t)bn + ni * 64 + wn * 16 + l15;
#pragma unroll
      for (int r = 0; r < 4; r++)
        C[(row + r) * N + col] = acc[mi][ni][r];
    }
  asm volatile("s_waitcnt vmcnt(0)" ::: "memory");  // drain wrap-staged loads
}

// ---------------- RoPE + scatter ----------------
__global__ void rope_scatter(const float* __restrict__ qkv, bf16_t* __restrict__ Qb,
                             bf16_t* __restrict__ Kb, bf16_t* __restrict__ Vt,
                             float* __restrict__ kOut, float* __restrict__ vOut) {
  int idx = blockIdx.x * 256 + threadIdx.x;
  int t = idx / 3072;
  int p = idx - t * 3072;
  const float NEG_L2T_64 = -0.20762050593046f;  // -log2(10000)/64
  const float SS = 0.08838834764831845f * 1.4426950408889634f;  // SCALE*log2(e)
  if (p < 2048) {  // Q
    int hh = p >> 6, pr = p & 63;
    int d0 = pr << 1;
    const float* src = qkv + (size_t)t * QKVN + hh * HD + d0;
    float a = src[0], b = src[1];
    int j0 = d0 & 63, j1 = (d0 + 1) & 63;
    float th0 = (float)t * exp2f((float)j0 * NEG_L2T_64);
    float th1 = (float)t * exp2f((float)j1 * NEG_L2T_64);
    float o0 = (a * cosf(th0) - b * sinf(th0)) * SS;
    float o1 = (b * cosf(th1) + a * sinf(th1)) * SS;
    bf16_t* dst = Qb + ((size_t)hh * SEQ + t) * HD + d0;
    dst[0] = (bf16_t)o0;
    dst[1] = (bf16_t)o1;
  } else if (p < 2560) {  // K
    int q2 = p - 2048;
    int kh = q2 >> 6, pr = q2 & 63;
    int d0 = pr << 1;
    const float* src = qkv + (size_t)t * QKVN + 4096 + kh * HD + d0;
    float a = src[0], b = src[1];
    int j0 = d0 & 63, j1 = (d0 + 1) & 63;
    float th0 = (float)t * exp2f((float)j0 * NEG_L2T_64);
    float th1 = (float)t * exp2f((float)j1 * NEG_L2T_64);
    float o0 = a * cosf(th0) - b * sinf(th0);
    float o1 = b * cosf(th1) + a * sinf(th1);
    bf16_t* dst = Kb + ((size_t)kh * SEQ + t) * HD + d0;
    dst[0] = (bf16_t)o0;
    dst[1] = (bf16_t)o1;
#pragma unroll
    for (int rep = 0; rep < 4; rep++) {
      float* kp = kOut + ((size_t)(kh * 4 + rep) * SEQ + t) * HD + d0;
      kp[0] = o0;
      kp[1] = o1;
    }
  } else {  // V
    int q2 = p - 2560;
    int kh = q2 >> 6, pr = q2 & 63;
    int d0 = pr << 1;
    const float* src = qkv + (size_t)t * QKVN + 5120 + kh * HD + d0;
    float a = src[0], b = src[1];
#pragma unroll
    for (int rep = 0; rep < 4; rep++) {
      float* vp = vOut + ((size_t)(kh * 4 + rep) * SEQ + t) * HD + d0;
      vp[0] = a;
      vp[1] = b;
    }
    // permuted key position for attention's PV slot ordering
    int tp = (t & ~31) + ((t & 12) << 1) + (t & 3) + ((t & 16) >> 2);
    Vt[((size_t)kh * HD + d0) * SEQ + tp] = (bf16_t)a;
    Vt[((size_t)kh * HD + d0 + 1) * SEQ + tp] = (bf16_t)b;
  }
}

// ---------------- Flash attention ----------------
__global__ __launch_bounds__(512, 2) void attn_kernel(const bf16_t* __restrict__ Qb,
                                                      const bf16_t* __restrict__ Kb,
                                                      const bf16_t* __restrict__ Vt,
                                                      bf16_t* __restrict__ AO) {
  __shared__ bf16_t Ks[2][8192];  // [buf][kc(4)][key(64)][d(32)]
  __shared__ bf16_t Vs[2][8192];  // [buf][kt(2)][d(128)][slot(32)]
  const int h = blockIdx.y, kh = h >> 2;
  const int qbase = blockIdx.x * 256;
  const int w = threadIdx.x >> 6, lane = threadIdx.x & 63;
  const int l15 = lane & 15, quad = lane >> 4;
  const bf16_t* KbH = Kb + (size_t)kh * SEQ * HD;
  const bf16_t* VtH = Vt + (size_t)kh * HD * SEQ;

  bf16x8 qf[2][4];
#pragma unroll
  for (int nq = 0; nq < 2; nq++) {
    const bf16_t* qp = Qb + ((size_t)h * SEQ + qbase + w * 32 + nq * 16 + l15) * HD + quad * 8;
#pragma unroll
    for (int kc = 0; kc < 4; kc++) qf[nq][kc] = *(const bf16x8*)(qp + kc * 32);
  }

  f32x4 acc[8][2] = {};
  float rsum[2] = {0.f, 0.f};

  auto stage = [&](int buf, int kt0) {
    if (w < 4) {
      int kc = w;
#pragma unroll
      for (int kg = 0; kg < 4; kg++) {
        const bf16_t* g = KbH + (size_t)(kt0 + kg * 16 + (lane >> 2)) * HD + kc * 32 + (lane & 3) * 8;
        async16(g, &Ks[buf][kc * 2048 + kg * 512]);
      }
    } else {
      int vi = w - 4, kt = vi >> 1, dg0 = (vi & 1) * 4;
#pragma unroll
      for (int j = 0; j < 4; j++) {
        int dg = dg0 + j;
        const bf16_t* g = VtH + (size_t)(dg * 16 + (lane >> 2)) * SEQ + kt0 + kt * 32 + (lane & 3) * 8;
        async16(g, &Vs[buf][kt * 4096 + dg * 512]);
      }
    }
  };

  stage(0, 0);
  int buf = 0;

  for (int kt0 = 0; kt0 < SEQ; kt0 += 64, buf ^= 1) {
    __syncthreads();
    if (kt0 + 64 < SEQ) stage(buf ^ 1, kt0 + 64);

    f32x4 sacc[4][2] = {};
#pragma unroll
    for (int mi = 0; mi < 4; mi++)
#pragma unroll
      for (int kc = 0; kc < 4; kc++) {
        bf16x8 kf = *(const bf16x8*)(&Ks[buf][(kc * 64 + mi * 16 + l15) * 32 + quad * 8]);
#pragma unroll
        for (int nq = 0; nq < 2; nq++)
          sacc[mi][nq] = mfma16(kf, qf[nq][kc], sacc[mi][nq]);
      }

    int pk[4][2][2];
#pragma unroll
    for (int mi = 0; mi < 4; mi++)
#pragma unroll
      for (int nq = 0; nq < 2; nq++) {
        float p0 = exp2f(sacc[mi][nq][0]);
        float p1 = exp2f(sacc[mi][nq][1]);
        float p2 = exp2f(sacc[mi][nq][2]);
        float p3 = exp2f(sacc[mi][nq][3]);
        rsum[nq] += (p0 + p1) + (p2 + p3);
        pk[mi][nq][0] = pack2(p0, p1);
        pk[mi][nq][1] = pack2(p2, p3);
      }

#pragma unroll
    for (int kt = 0; kt < 2; kt++) {
#pragma unroll
      for (int nq = 0; nq < 2; nq++) {
        int4v dw;
        dw[0] = pk[2 * kt][nq][0];
        dw[1] = pk[2 * kt][nq][1];
        dw[2] = pk[2 * kt + 1][nq][0];
        dw[3] = pk[2 * kt + 1][nq][1];
        bf16x8 pf = __builtin_bit_cast(bf16x8, dw);
#pragma unroll
        for (int dt = 0; dt < 8; dt++) {
          bf16x8 vf = *(const bf16x8*)(&Vs[buf][(kt * 128 + dt * 16 + l15) * 32 + quad * 8]);
          acc[dt][nq] = mfma16(vf, pf, acc[dt][nq]);
        }
      }
    }
  }

#pragma unroll
  for (int nq = 0; nq < 2; nq++) {
    float rs = rsum[nq];
    rs += __shfl_xor(rs, 16);
    rs += __shfl_xor(rs, 32);
    float inv = 1.0f / rs;
    int q = qbase + w * 32 + nq * 16 + l15;
#pragma unroll
    for (int dt = 0; dt < 8; dt++) {
      bf16x4 o = { (bf16_t)(acc[dt][nq][0] * inv), (bf16_t)(acc[dt][nq][1] * inv),
                   (bf16_t)(acc[dt][nq][2] * inv), (bf16_t)(acc[dt][nq][3] * inv) };
      *(bf16x4*)(AO + (size_t)q * DIM + h * HD + dt * 16 + quad * 4) = o;
    }
  }
}

extern "C" void kernel_launch(void* const* d_in, const int* in_sizes, int n_in,
                              void* d_out, int out_size, void* d_ws, size_t ws_size,
                              hipStream_t stream) {
  const float* x = (const float*)d_in[0];
  const float* wq = (const float*)d_in[1];
  const float* wk = (const float*)d_in[2];
  const float* wv = (const float*)d_in[3];
  const float* wo = (const float*)d_in[4];
  float* out = (float*)d_out;
  float* kOut = out + (size_t)SEQ * DIM;
  float* vOut = kOut + (size_t)NH * SEQ * HD;

  char* ws = (char*)d_ws;
  bf16_t* Xb = (bf16_t*)ws;                          // 16 MB; later aliased as AO
  bf16_t* WT = (bf16_t*)(ws + 16777216);             // 48 MB: [wq^T|wk^T|wv^T]
  float* QKV = (float*)(ws + 67108864);              // 48 MB fp32
  bf16_t* WoT = (bf16_t*)(ws + 67108864);            // alias (QKV dead by then)
  bf16_t* Qb = (bf16_t*)(ws + 117440512);            // 16 MB
  bf16_t* Kb = (bf16_t*)(ws + 134217728);            // 4 MB
  bf16_t* Vt = (bf16_t*)(ws + 138412032);            // 4 MB (slot-permuted keys)
  bf16_t* AO = Xb;

  dim3 tb(32, 8);
  cast_x<<<8192, 256, 0, stream>>>(x, Xb);
  tcast<<<dim3(128, 128), tb, 0, stream>>>(wq, WT, 4096, 4096);
  tcast<<<dim3(32, 128), tb, 0, stream>>>(wk, WT + (size_t)4096 * 4096, 1024, 4096);
  tcast<<<dim3(32, 128), tb, 0, stream>>>(wv, WT + (size_t)5120 * 4096, 1024, 4096);
  gemm256<3><<<dim3(32, 8), 512, 0, stream>>>(Xb, WT, QKV, 2048, 6144, 4096);
  rope_scatter<<<24576, 256, 0, stream>>>(QKV, Qb, Kb, Vt, kOut, vOut);
  tcast<<<dim3(128, 128), tb, 0, stream>>>(wo, WoT, 4096, 4096);
  attn_kernel<<<dim3(8, 32), 512, 0, stream>>>(Qb, Kb, Vt, AO);
  gemm256<2><<<dim3(32, 8), 512, 0, stream>>>(AO, WoT, out, 2048, 4096, 4096);
}